// Round 8
// baseline (487.823 us; speedup 1.0000x reference)
//
#include <hip/hip_runtime.h>

#define BATCH 32
#define NPTS  1024
#define NTOT  (BATCH * NPTS)   // 32768 points

typedef _Float16 half8  __attribute__((ext_vector_type(8)));
typedef float    f32x4  __attribute__((ext_vector_type(4)));

// ---------- helpers ----------

__device__ __forceinline__ float fast_tanh(float x) {
  float ax = fabsf(x);
  float e  = __expf(-2.0f * ax);
  float t  = (1.0f - e) / (1.0f + e);
  return x < 0.0f ? -t : t;
}

// Jacobi polys for a=b=1, degree 3: p1=2t, p2=3.75t^2-0.75, p3=7t^3-3t
__device__ __forceinline__ void jacobi4(float t, float& p0, float& p1, float& p2, float& p3) {
  float t2 = t * t;
  p0 = 1.0f;
  p1 = 2.0f * t;
  p2 = 3.75f * t2 - 0.75f;
  p3 = t * (7.0f * t2 - 3.0f);
}

// monotone float<->uint encoding for atomicMax over signed floats
__device__ __forceinline__ unsigned encf(float f) {
  unsigned b = __float_as_uint(f);
  return b ^ ((unsigned)((int)b >> 31) | 0x80000000u);
}
__device__ __forceinline__ float decf(unsigned u) {
  unsigned b = (u & 0x80000000u) ? (u ^ 0x80000000u) : ~u;
  return __uint_as_float(b);
}

// ---------- zero workspace accumulators ----------
__global__ void zero_ws(unsigned* __restrict__ p, int n) {
  int i = blockIdx.x * 256 + threadIdx.x;
  if (i < n) p[i] = 0u;
}

// ---------- weight preconversion: fp32 (C_in, C_out, 4) -> fp16 x64, fragment layout ----------
// wh[(ot*nslot + s)*BN + oL] = half8{ 64*w[2s][ot*BN+oL][0..3], 64*w[2s+1][...][0..3] }
__global__ void conv_w16(const float* __restrict__ w, half8* __restrict__ wh,
                         int C_in, int C_out, int BN) {
  const int nslot = C_in >> 1;
  int tid = blockIdx.x * 256 + threadIdx.x;
  int oL = tid % BN;
  int r  = tid / BN;
  int s  = r % nslot;
  int ot = r / nslot;
  int i  = s << 1;
  int o  = ot * BN + oL;
  const float4 wa = *(const float4*)(w + (((size_t)i * C_out + o) << 2));
  const float4 wb = *(const float4*)(w + (((size_t)(i + 1) * C_out + o) << 2));
  half8 h;
  h[0] = (_Float16)(wa.x * 64.0f); h[1] = (_Float16)(wa.y * 64.0f);
  h[2] = (_Float16)(wa.z * 64.0f); h[3] = (_Float16)(wa.w * 64.0f);
  h[4] = (_Float16)(wb.x * 64.0f); h[5] = (_Float16)(wb.y * 64.0f);
  h[6] = (_Float16)(wb.z * 64.0f); h[7] = (_Float16)(wb.w * 64.0f);
  wh[tid] = h;
}

// ---------- activation+poly pass: y fp32 -> PA half8 (MFMA-A fragment layout) ----------
// PA[(b*nslot + s)*1024 + n] = {1, 2t_a, p2_a, p3_a, 1, 2t_c, p2_c, p3_c},
// t = tanh((y - m) * rstd) computed in fp32, rounded once to fp16 (same numerics as R7).
// grid = 128*nslot blocks x 256 threads (1 point-slot per thread).
__global__ __launch_bounds__(256) void act_poly(
    const float* __restrict__ y, const float2* __restrict__ st,
    half8* __restrict__ PA, int nslot)
{
  int tid = blockIdx.x * 256 + threadIdx.x;
  int n   = tid & 1023;
  int r   = tid >> 10;            // b*nslot + s
  int s   = r % nslot;
  int b   = r / nslot;
  int c0  = s << 1;
  const int C = nslot << 1;
  float va = y[(((size_t)(b * C + c0)) << 10) + n];
  float vc = y[(((size_t)(b * C + c0 + 1)) << 10) + n];
  float2 s0 = st[c0], s1 = st[c0 + 1];
  float a = fast_tanh((va - s0.x) * s0.y);
  float c = fast_tanh((vc - s1.x) * s1.y);
  float as = a * a, cs = c * c;
  half8 h;
  h[0] = (_Float16)1.0f;
  h[1] = (_Float16)(a + a);
  h[2] = (_Float16)(3.75f * as - 0.75f);
  h[3] = (_Float16)(a * (7.0f * as - 3.0f));
  h[4] = (_Float16)1.0f;
  h[5] = (_Float16)(c + c);
  h[6] = (_Float16)(3.75f * cs - 0.75f);
  h[7] = (_Float16)(c * (7.0f * cs - 3.0f));
  PA[((size_t)r << 10) + n] = h;
}

// ---------- activation pass: y <- tanh(norm(y)) IN PLACE, fp32 (L7 input only) ----------
__global__ __launch_bounds__(256) void act_tanh(
    float* y, const float2* __restrict__ st, int C)
{
  size_t i = (((size_t)blockIdx.x << 8) + threadIdx.x) << 2;
  int c = (int)((i >> 10) % (unsigned)C);
  float2 s = st[c];
  float4 v = *(float4*)(y + i);
  v.x = fast_tanh((v.x - s.x) * s.y);
  v.y = fast_tanh((v.y - s.x) * s.y);
  v.z = fast_tanh((v.z - s.x) * s.y);
  v.w = fast_tanh((v.w - s.x) * s.y);
  *(float4*)(y + i) = v;
}

// ---------- MFMA KAN layer v4 ----------
// Block: 128 pts x BN outs (BN = NBW*64), 2*NBW waves, 4x4 frags of 16x16x32.
// PRE=true : A-frags loaded directly from PA (half8) — pure load+MFMA K-loop.
// PRE=false: A-frags from fp32 tanh buffer + inline Jacobi (L7: PA would be 128MB).
// Verified layouts: A m=lane&15, k=quad*8+j; C/D row(M)=quad*4+reg, col(N)=lane&15.
// Weights pre-scaled x64 (undone in epilogue). Epilogue:
//   out != nullptr : write fp32 y + per-(o, xblock) partials to spart
//   out == nullptr : L5 mode -> atomicAdd channel sums + per-(b,o) atomicMax
template<int NBW, bool PRE>
__global__ __launch_bounds__(NBW * 128, 2) void kan_mfma4(
    const float* __restrict__ T,       // (B, C_in, N) fp32 tanh values (PRE=false)
    const half8* __restrict__ PA,      // (B, nslot, N) poly frags (PRE=true)
    const half8* __restrict__ wh,      // preconverted weights (x64)
    const float* __restrict__ bias,    // (B, C_out) or nullptr
    float*       __restrict__ out,     // (B, C_out, N) fp32 or nullptr
    float2*      __restrict__ spart,   // (C_out, 256) partials
    float*       __restrict__ stat_acc,
    unsigned*    __restrict__ max_acc,
    int C_in, int C_out)
{
  constexpr int BN = NBW * 64;
  const int nslot = C_in >> 1;
  __shared__ float sredS[BN][2], sredS2[BN][2], sredM[BN][2];

  const int t    = threadIdx.x;
  const int lane = t & 63;
  const int col  = lane & 15;
  const int quad = lane >> 4;
  const int wv   = t >> 6;
  const int wm   = wv & 1;
  const int wn   = wv >> 1;
  const int b    = blockIdx.x >> 3;
  const int n0   = (blockIdx.x & 7) << 7;
  const int o0   = blockIdx.y * BN;

  f32x4 acc[4][4];
#pragma unroll
  for (int i = 0; i < 4; ++i)
#pragma unroll
    for (int j = 0; j < 4; ++j)
#pragma unroll
      for (int k = 0; k < 4; ++k) acc[i][j][k] = 0.0f;

  const float* Tp = T  + (((size_t)(b * C_in + (quad << 1))) << 10) + n0 + (wm << 6) + col;
  const half8* Ap = PA + (((size_t)(b * nslot + quad)) << 10) + n0 + (wm << 6) + col;
  const half8* Bp = wh + (size_t)blockIdx.y * nslot * BN + (size_t)quad * BN + wn * 64 + col;

  for (int s4 = 0; s4 < nslot; s4 += 4) {
    half8 af[4], bf[4];
    if (PRE) {
#pragma unroll
      for (int f = 0; f < 4; ++f) {
        af[f] = Ap[f << 4];
        bf[f] = Bp[f << 4];
      }
      Ap += (size_t)4 << 10;
      Bp += (size_t)4 * BN;
    } else {
      float t0[4], t1[4];
#pragma unroll
      for (int f = 0; f < 4; ++f) {
        t0[f] = Tp[f << 4];
        t1[f] = Tp[(f << 4) + 1024];
        bf[f] = Bp[f << 4];
      }
      Tp += (size_t)8 << 10;
      Bp += (size_t)4 * BN;
#pragma unroll
      for (int f = 0; f < 4; ++f) {
        float a = t0[f], c = t1[f];
        float as = a * a, cs = c * c;
        half8 h;
        h[0] = (_Float16)1.0f;
        h[1] = (_Float16)(a + a);
        h[2] = (_Float16)(3.75f * as - 0.75f);
        h[3] = (_Float16)(a * (7.0f * as - 3.0f));
        h[4] = (_Float16)1.0f;
        h[5] = (_Float16)(c + c);
        h[6] = (_Float16)(3.75f * cs - 0.75f);
        h[7] = (_Float16)(c * (7.0f * cs - 3.0f));
        af[f] = h;
      }
    }
#pragma unroll
    for (int fm = 0; fm < 4; ++fm)
#pragma unroll
      for (int fn = 0; fn < 4; ++fn)
        acc[fm][fn] = __builtin_amdgcn_mfma_f32_16x16x32_f16(af[fm], bf[fn], acc[fm][fn], 0, 0, 0);
  }

  // ---- epilogue: unscale, bias, fp32 write, fused BN stats ----
  const float inv64 = 0.015625f;
#pragma unroll
  for (int fn = 0; fn < 4; ++fn) {
    const int cl = (wn << 6) + (fn << 4) + col;
    const int o  = o0 + cl;
    const float bb = bias ? bias[b * C_out + o] : 0.0f;
    float s = 0.f, s2 = 0.f, mx = -3.4e38f;
#pragma unroll
    for (int fm = 0; fm < 4; ++fm) {
      float v0 = acc[fm][fn][0] * inv64 + bb;
      float v1 = acc[fm][fn][1] * inv64 + bb;
      float v2 = acc[fm][fn][2] * inv64 + bb;
      float v3 = acc[fm][fn][3] * inv64 + bb;
      if (out) {
        *(float4*)(out + (((size_t)(b * C_out + o)) << 10) + n0 + (wm << 6) + (fm << 4) + (quad << 2)) =
            make_float4(v0, v1, v2, v3);
      }
      s  += v0 + v1 + v2 + v3;
      s2 += v0 * v0 + v1 * v1 + v2 * v2 + v3 * v3;
      mx  = fmaxf(fmaxf(v0, v1), fmaxf(fmaxf(v2, v3), mx));
    }
    s  += __shfl_down(s, 32);  s  += __shfl_down(s, 16);
    s2 += __shfl_down(s2, 32); s2 += __shfl_down(s2, 16);
    mx  = fmaxf(mx, __shfl_down(mx, 32)); mx = fmaxf(mx, __shfl_down(mx, 16));
    if (lane < 16) {
      sredS [cl][wm] = s;
      sredS2[cl][wm] = s2;
      sredM [cl][wm] = mx;
    }
  }
  __syncthreads();
  if (t < BN) {
    const int o = o0 + t;
    float s  = sredS [t][0] + sredS [t][1];
    float s2 = sredS2[t][0] + sredS2[t][1];
    if (out) {
      spart[(o << 8) + blockIdx.x] = make_float2(s, s2);
    } else {
      float mx = fmaxf(sredM[t][0], sredM[t][1]);
      atomicAdd(&stat_acc[o], s);
      atomicAdd(&stat_acc[C_out + o], s2);
      atomicMax(&max_acc[b * C_out + o], encf(mx));
    }
  }
}

// ---------- fp32 KAN layer (L1 only: C_in=2) ----------
template<int BM, int BN>
__global__ __launch_bounds__(256) void kan_gemm(
    const float*  __restrict__ in, const float2* __restrict__ stats,
    const float*  __restrict__ w, float* __restrict__ out,
    float2* __restrict__ spart, int C_in, int C_out)
{
  static_assert(BM * BN == 256 * 64, "8x8-per-thread tile requires BM*BN == 16384");
  constexpr int TM = BM / 8;
  constexpr int AE = 8 * BM / 256;
  constexpr int BE = 8 * BN / 256;
  __shared__ __align__(16) float As[32][BM];
  __shared__ __align__(16) float Bs[32][BN];

  const int t  = threadIdx.x;
  const int tpb = NPTS / BM;
  const int b  = blockIdx.x / tpb;
  const int n0 = (blockIdx.x % tpb) * BM;
  const int o0 = blockIdx.y * BN;
  const int tm = t % TM;
  const int to = t / TM;

  float acc[2][4][2][4];
#pragma unroll
  for (int a = 0; a < 2; ++a)
#pragma unroll
    for (int c = 0; c < 4; ++c)
#pragma unroll
      for (int d = 0; d < 2; ++d)
#pragma unroll
        for (int e = 0; e < 4; ++e) acc[a][c][d][e] = 0.0f;

  const int nch = (C_in + 7) >> 3;
  for (int ch = 0; ch < nch; ++ch) {
    const int i0 = ch << 3;
    __syncthreads();
#pragma unroll
    for (int r = 0; r < AE; ++r) {
      int e  = t + (r << 8);
      int il = e / BM, n = e % BM;
      int i  = i0 + il;
      float p0 = 0.f, p1 = 0.f, p2 = 0.f, p3 = 0.f;
      if (i < C_in) {
        float v = in[((size_t)(b * C_in + i) << 10) + n0 + n];
        if (stats) { float2 s = stats[i]; v = (v - s.x) * s.y; }
        jacobi4(fast_tanh(v), p0, p1, p2, p3);
      }
      As[(il << 2) + 0][n] = p0;
      As[(il << 2) + 1][n] = p1;
      As[(il << 2) + 2][n] = p2;
      As[(il << 2) + 3][n] = p3;
    }
#pragma unroll
    for (int r = 0; r < BE; ++r) {
      int e  = t + (r << 8);
      int il = e / BN, o = e % BN;
      int i  = i0 + il;
      float4 wv = make_float4(0.f, 0.f, 0.f, 0.f);
      if (i < C_in) wv = *(const float4*)(w + (((size_t)i * C_out + o0 + o) << 2));
      Bs[(il << 2) + 0][o] = wv.x;
      Bs[(il << 2) + 1][o] = wv.y;
      Bs[(il << 2) + 2][o] = wv.z;
      Bs[(il << 2) + 3][o] = wv.w;
    }
    __syncthreads();
#pragma unroll 8
    for (int k = 0; k < 32; ++k) {
      const float4 a0 = *(const float4*)&As[k][tm << 2];
      const float4 a1 = *(const float4*)&As[k][(BM / 2) + (tm << 2)];
      const float4 b0 = *(const float4*)&Bs[k][to << 2];
      const float4 b1 = *(const float4*)&Bs[k][(BN / 2) + (to << 2)];
      const float am[2][4] = {{a0.x, a0.y, a0.z, a0.w}, {a1.x, a1.y, a1.z, a1.w}};
      const float bo[2][4] = {{b0.x, b0.y, b0.z, b0.w}, {b1.x, b1.y, b1.z, b1.w}};
#pragma unroll
      for (int oh = 0; oh < 2; ++oh)
#pragma unroll
        for (int oj = 0; oj < 4; ++oj) {
          const float bv = bo[oh][oj];
#pragma unroll
          for (int mh = 0; mh < 2; ++mh)
#pragma unroll
            for (int mj = 0; mj < 4; ++mj)
              acc[oh][oj][mh][mj] = fmaf(bv, am[mh][mj], acc[oh][oj][mh][mj]);
        }
    }
  }

#pragma unroll
  for (int oh = 0; oh < 2; ++oh)
#pragma unroll
    for (int oj = 0; oj < 4; ++oj) {
      const int o = o0 + oh * (BN / 2) + (to << 2) + oj;
      float s = 0.f, s2 = 0.f;
#pragma unroll
      for (int mh = 0; mh < 2; ++mh) {
        float4 v = make_float4(acc[oh][oj][mh][0], acc[oh][oj][mh][1],
                               acc[oh][oj][mh][2], acc[oh][oj][mh][3]);
        *(float4*)(out + (((size_t)(b * C_out + o)) << 10) + n0 + mh * (BM / 2) + (tm << 2)) = v;
        s  += v.x + v.y + v.z + v.w;
        s2 += v.x * v.x + v.y * v.y + v.z * v.z + v.w * v.w;
      }
#pragma unroll
      for (int off = TM / 2; off > 0; off >>= 1) {
        s  += __shfl_down(s, off, TM);
        s2 += __shfl_down(s2, off, TM);
      }
      if (tm == 0) spart[(o << 8) + blockIdx.x] = make_float2(s, s2);
    }
}

// ---------- reduce per-block partials -> BN stats ----------
__global__ __launch_bounds__(256) void bn_finalize2(
    const float2* __restrict__ spart, float2* __restrict__ stats, int C, int nxb)
{
  int c = blockIdx.x, t = threadIdx.x;
  float s = 0.f, s2 = 0.f;
  if (t < nxb) { float2 p = spart[(c << 8) + t]; s = p.x; s2 = p.y; }
#pragma unroll
  for (int off = 32; off > 0; off >>= 1) {
    s  += __shfl_down(s, off);
    s2 += __shfl_down(s2, off);
  }
  __shared__ float rs[4], rs2[4];
  int wid = t >> 6;
  if ((t & 63) == 0) { rs[wid] = s; rs2[wid] = s2; }
  __syncthreads();
  if (t == 0) {
    s  = rs[0] + rs[1] + rs[2] + rs[3];
    s2 = rs2[0] + rs2[1] + rs2[2] + rs2[3];
    float m   = s * (1.0f / NTOT);
    float var = s2 * (1.0f / NTOT) - m * m;
    stats[c] = make_float2(m, rsqrtf(var + 1e-5f));
  }
}

// ---------- finalize layer-5 stats from atomic accumulators ----------
__global__ void bn_finalize(const float* __restrict__ stat_acc,
                            float2* __restrict__ stats, int C) {
  int c = blockIdx.x * 256 + threadIdx.x;
  if (c < C) {
    float m   = stat_acc[c] * (1.0f / NTOT);
    float var = stat_acc[C + c] * (1.0f / NTOT) - m * m;
    stats[c] = make_float2(m, rsqrtf(var + 1e-5f));
  }
}

// ---------- global-feature branch of layer 6, parallel ----------
__global__ __launch_bounds__(256) void pool_const6p(
    const unsigned* __restrict__ max_acc, const float2* __restrict__ stats5,
    const float* __restrict__ w6, float* __restrict__ cst)
{
  __shared__ __align__(16) float4 P[32][64];
  const int t  = threadIdx.x;
  const int ot = blockIdx.x;
  const int c0 = blockIdx.y << 6;
#pragma unroll
  for (int it = 0; it < 8; ++it) {
    int idx = t + (it << 8);
    int b = idx >> 6, cl = idx & 63;
    int c = c0 + cl;
    float mx = decf(max_acc[(b << 10) + c]);
    float2 s = stats5[c];
    float tt = fast_tanh((mx - s.x) * s.y);
    float p0, p1, p2, p3; jacobi4(tt, p0, p1, p2, p3);
    P[b][cl] = make_float4(p0, p1, p2, p3);
  }
  __syncthreads();
  const int oL = t & 63;
  const int bg = t >> 6;
  const int o  = (ot << 6) + oL;
  float acc[8];
#pragma unroll
  for (int i = 0; i < 8; ++i) acc[i] = 0.f;
  for (int cl = 0; cl < 64; ++cl) {
    const float4 wv = *(const float4*)(w6 + (((size_t)(64 + c0 + cl) * 512 + o) << 2));
#pragma unroll
    for (int bb = 0; bb < 8; ++bb) {
      float4 p = P[(bg << 3) + bb][cl];
      acc[bb] += p.x * wv.x + p.y * wv.y + p.z * wv.z + p.w * wv.w;
    }
  }
#pragma unroll
  for (int bb = 0; bb < 8; ++bb)
    atomicAdd(&cst[(((bg << 3) + bb) << 9) + o], acc[bb]);
}

// ---------- final layer: PA9 (64 slots of fp16 polys) -> C_out=3 fp32 ----------
__global__ __launch_bounds__(256) void kan_final(
    const half8* __restrict__ PA, const float* __restrict__ w, float* __restrict__ out)
{
  int g = blockIdx.x * 256 + threadIdx.x;
  int b = g >> 10, n = g & 1023;
  float a0 = 0.f, a1 = 0.f, a2 = 0.f;
  for (int s = 0; s < 64; ++s) {
    half8 h = PA[(((size_t)(b * 64 + s)) << 10) + n];
#pragma unroll
    for (int half_i = 0; half_i < 2; ++half_i) {
      int i = (s << 1) + half_i;
      float p0 = (float)h[half_i * 4 + 0], p1 = (float)h[half_i * 4 + 1];
      float p2 = (float)h[half_i * 4 + 2], p3 = (float)h[half_i * 4 + 3];
      const float4 w0 = *(const float4*)(w + ((i * 3 + 0) << 2));
      const float4 w1 = *(const float4*)(w + ((i * 3 + 1) << 2));
      const float4 w2 = *(const float4*)(w + ((i * 3 + 2) << 2));
      a0 += p0 * w0.x + p1 * w0.y + p2 * w0.z + p3 * w0.w;
      a1 += p0 * w1.x + p1 * w1.y + p2 * w1.z + p3 * w1.w;
      a2 += p0 * w2.x + p1 * w2.y + p2 * w2.z + p3 * w2.w;
    }
  }
  out[((b * 3 + 0) << 10) + n] = a0;
  out[((b * 3 + 1) << 10) + n] = a1;
  out[((b * 3 + 2) << 10) + n] = a2;
}

// ---------- launch ----------
extern "C" void kernel_launch(void* const* d_in, const int* in_sizes, int n_in,
                              void* d_out, int out_size, void* d_ws, size_t ws_size,
                              hipStream_t stream) {
  const float* x   = (const float*)d_in[0];
  const float* w1  = (const float*)d_in[1];
  const float* w2  = (const float*)d_in[2];
  const float* w3  = (const float*)d_in[3];
  const float* w4  = (const float*)d_in[4];
  const float* w5  = (const float*)d_in[5];
  const float* w6  = (const float*)d_in[6];
  const float* w7  = (const float*)d_in[7];
  const float* w8  = (const float*)d_in[8];
  const float* w9  = (const float*)d_in[9];
  const float* w10 = (const float*)d_in[10];

  float* ws = (float*)d_ws;
  // misc region (floats)
  float*    stat_acc = ws + 0;                      // 2048
  unsigned* maxenc   = (unsigned*)(ws + 2048);      // 32768
  float*    cst6     = ws + 34816;                  // 16384 (zeroed)
  float2*   spart    = (float2*)(ws + 51200);       // 131072 float2 -> ends 313344
  float2*   stats1   = (float2*)(ws + 313344);
  float2*   stats2   = stats1 + 64;
  float2*   stats3   = stats2 + 64;
  float2*   stats4   = stats3 + 64;
  float2*   stats5   = stats4 + 128;
  float2*   stats6   = stats5 + 1024;
  float2*   stats7   = stats6 + 512;
  float2*   stats8   = stats7 + 256;
  float2*   stats9   = stats8 + 128;
  // fp16 weight pool (half8 units) @ float offset 318464 (ends < 1048576 floats)
  half8*    whbase = (half8*)(ws + 318464);
  half8*    h2 = whbase + 0;        // 32*64    = 2048
  half8*    h3 = whbase + 2048;     // 2048
  half8*    h4 = whbase + 4096;     // 32*128   = 4096
  half8*    h5 = whbase + 8192;     // 64*1024  = 65536
  half8*    h6 = whbase + 73728;    // 32*512   = 16384
  half8*    h7 = whbase + 90112;    // 256*256  = 65536
  half8*    h8 = whbase + 155648;   // 128*128  = 16384
  half8*    h9 = whbase + 172032;   // 64*128   = 8192
  // data regions (floats), liveness-based tenants:
  //   Yv (4M): y1,y2,y3,y4,y8,y9    PB (8M): PA1,PA3,PA4,y7,PA8,PA9
  //   PC (4M): PA2                  PD (16M): y6/t6, PA7
  float* P  = ws + 1048576;
  float* Yv = P;
  float* PB = P + 4194304;
  float* PC = P + 12582912;
  float* PD = P + 16777216;        // ends P+32M -> total ~132 MB
  half8* PA1 = (half8*)PB;
  half8* PA2 = (half8*)PC;
  half8* PA3 = (half8*)PB;
  half8* PA4 = (half8*)PB;
  float* y7  = PB;
  half8* PA7 = (half8*)PD;
  half8* PA8 = (half8*)PB;
  half8* PA9 = (half8*)PB;
  float* y6  = PD;

  dim3 blk(256);
  zero_ws<<<200, blk, 0, stream>>>((unsigned*)ws, 51200);
  // preconvert weights
  conv_w16<<<8,   blk, 0, stream>>>(w2, h2, 64, 64, 64);
  conv_w16<<<8,   blk, 0, stream>>>(w3, h3, 64, 64, 64);
  conv_w16<<<16,  blk, 0, stream>>>(w4, h4, 64, 128, 128);
  conv_w16<<<256, blk, 0, stream>>>(w5, h5, 128, 1024, 128);
  conv_w16<<<64,  blk, 0, stream>>>(w6, h6, 64, 512, 128);   // local rows 0..63
  conv_w16<<<256, blk, 0, stream>>>(w7, h7, 512, 256, 128);
  conv_w16<<<64,  blk, 0, stream>>>(w8, h8, 256, 128, 128);
  conv_w16<<<32,  blk, 0, stream>>>(w9, h9, 128, 128, 128);

  // L1: 2 -> 64 fp32
  kan_gemm<256, 64><<<dim3(128, 1), blk, 0, stream>>>(x, nullptr, w1, Yv, spart, 2, 64);
  bn_finalize2<<<64, blk, 0, stream>>>(spart, stats1, 64, 128);
  act_poly<<<128 * 32, blk, 0, stream>>>(Yv, stats1, PA1, 32);
  // L2: 64 -> 64
  kan_mfma4<1, true><<<dim3(256, 1), 128, 0, stream>>>(nullptr, PA1, h2, nullptr, Yv, spart, nullptr, nullptr, 64, 64);
  bn_finalize2<<<64, blk, 0, stream>>>(spart, stats2, 64, 256);
  act_poly<<<128 * 32, blk, 0, stream>>>(Yv, stats2, PA2, 32);               // kept for L6
  // L3: 64 -> 64
  kan_mfma4<1, true><<<dim3(256, 1), 128, 0, stream>>>(nullptr, PA2, h3, nullptr, Yv, spart, nullptr, nullptr, 64, 64);
  bn_finalize2<<<64, blk, 0, stream>>>(spart, stats3, 64, 256);
  act_poly<<<128 * 32, blk, 0, stream>>>(Yv, stats3, PA3, 32);
  // L4: 64 -> 128
  kan_mfma4<2, true><<<dim3(256, 1), blk, 0, stream>>>(nullptr, PA3, h4, nullptr, Yv, spart, nullptr, nullptr, 64, 128);
  bn_finalize2<<<128, blk, 0, stream>>>(spart, stats4, 128, 256);
  act_poly<<<128 * 64, blk, 0, stream>>>(Yv, stats4, PA4, 64);
  // L5: 128 -> 1024, fused stats + maxpool, no materialization
  kan_mfma4<2, true><<<dim3(256, 8), blk, 0, stream>>>(nullptr, PA4, h5, nullptr, nullptr, nullptr, stat_acc, maxenc, 128, 1024);
  bn_finalize<<<4, blk, 0, stream>>>(stat_acc, stats5, 1024);
  // gf branch of layer 6
  pool_const6p<<<dim3(8, 16), blk, 0, stream>>>(maxenc, stats5, w6, cst6);
  // L6: 64 (local, PA2) -> 512 + gf bias
  kan_mfma4<2, true><<<dim3(256, 4), blk, 0, stream>>>(nullptr, PA2, h6, cst6, y6, spart, nullptr, nullptr, 64, 512);
  bn_finalize2<<<512, blk, 0, stream>>>(spart, stats6, 512, 256);
  act_tanh<<<32 * 512, blk, 0, stream>>>(y6, stats6, 512);                   // t6 in place
  // L7: 512 -> 256 (inline Jacobi from fp32 t6; PA6 would be 128 MB)
  kan_mfma4<2, false><<<dim3(256, 2), blk, 0, stream>>>(y6, nullptr, h7, nullptr, y7, spart, nullptr, nullptr, 512, 256);
  bn_finalize2<<<256, blk, 0, stream>>>(spart, stats7, 256, 256);
  act_poly<<<128 * 128, blk, 0, stream>>>(y7, stats7, PA7, 128);
  // L8: 256 -> 128
  kan_mfma4<2, true><<<dim3(256, 1), blk, 0, stream>>>(nullptr, PA7, h8, nullptr, Yv, spart, nullptr, nullptr, 256, 128);
  bn_finalize2<<<128, blk, 0, stream>>>(spart, stats8, 128, 256);
  act_poly<<<128 * 64, blk, 0, stream>>>(Yv, stats8, PA8, 64);
  // L9: 128 -> 128
  kan_mfma4<2, true><<<dim3(256, 1), blk, 0, stream>>>(nullptr, PA8, h9, nullptr, Yv, spart, nullptr, nullptr, 128, 128);
  bn_finalize2<<<128, blk, 0, stream>>>(spart, stats9, 128, 256);
  act_poly<<<128 * 64, blk, 0, stream>>>(Yv, stats9, PA9, 64);
  // L10: 128 -> 3 (fp16 polys x fp32 weights)
  kan_final<<<128, blk, 0, stream>>>(PA9, w10, (float*)d_out);
}

// Round 9
// 448.402 us; speedup vs baseline: 1.0879x; 1.0879x over previous
//
#include <hip/hip_runtime.h>

#define BATCH 32
#define NPTS  1024
#define NTOT  (BATCH * NPTS)   // 32768 points

typedef _Float16 half8  __attribute__((ext_vector_type(8)));
typedef float    f32x4  __attribute__((ext_vector_type(4)));

// ---------- helpers ----------

__device__ __forceinline__ float fast_tanh(float x) {
  float ax = fabsf(x);
  float e  = __expf(-2.0f * ax);
  float t  = (1.0f - e) / (1.0f + e);
  return x < 0.0f ? -t : t;
}

// Jacobi polys for a=b=1, degree 3: p1=2t, p2=3.75t^2-0.75, p3=7t^3-3t
__device__ __forceinline__ void jacobi4(float t, float& p0, float& p1, float& p2, float& p3) {
  float t2 = t * t;
  p0 = 1.0f;
  p1 = 2.0f * t;
  p2 = 3.75f * t2 - 0.75f;
  p3 = t * (7.0f * t2 - 3.0f);
}

// monotone float<->uint encoding for atomicMax over signed floats
__device__ __forceinline__ unsigned encf(float f) {
  unsigned b = __float_as_uint(f);
  return b ^ ((unsigned)((int)b >> 31) | 0x80000000u);
}
__device__ __forceinline__ float decf(unsigned u) {
  unsigned b = (u & 0x80000000u) ? (u ^ 0x80000000u) : ~u;
  return __uint_as_float(b);
}

// ---------- zero workspace accumulators ----------
__global__ void zero_ws(unsigned* __restrict__ p, int n) {
  int i = blockIdx.x * 256 + threadIdx.x;
  if (i < n) p[i] = 0u;
}

// ---------- weight preconversion: fp32 (C_in, C_out, 4) -> fp16 x64, fragment layout ----------
__global__ void conv_w16(const float* __restrict__ w, half8* __restrict__ wh,
                         int C_in, int C_out, int BN) {
  const int nslot = C_in >> 1;
  int tid = blockIdx.x * 256 + threadIdx.x;
  int oL = tid % BN;
  int r  = tid / BN;
  int s  = r % nslot;
  int ot = r / nslot;
  int i  = s << 1;
  int o  = ot * BN + oL;
  const float4 wa = *(const float4*)(w + (((size_t)i * C_out + o) << 2));
  const float4 wb = *(const float4*)(w + (((size_t)(i + 1) * C_out + o) << 2));
  half8 h;
  h[0] = (_Float16)(wa.x * 64.0f); h[1] = (_Float16)(wa.y * 64.0f);
  h[2] = (_Float16)(wa.z * 64.0f); h[3] = (_Float16)(wa.w * 64.0f);
  h[4] = (_Float16)(wb.x * 64.0f); h[5] = (_Float16)(wb.y * 64.0f);
  h[6] = (_Float16)(wb.z * 64.0f); h[7] = (_Float16)(wb.w * 64.0f);
  wh[tid] = h;
}

// ---------- merged BN-finalize + activation+poly: y fp32 -> PA half8 (A-frag layout) ----------
// Each block covers 256 points of one (b, s) channel-pair; it first re-reduces the
// 256 per-block spart partials for its 2 channels (L2-cached, cheap), then computes
// t = tanh(norm(y)) and polys in fp32, rounding once to fp16 (R7-identical numerics).
__global__ __launch_bounds__(256) void act_poly(
    const float* __restrict__ y, const float2* __restrict__ spart,
    half8* __restrict__ PA, int nslot, int nxb)
{
  const int tid = blockIdx.x * 256 + threadIdx.x;
  const int t   = threadIdx.x;
  const int n   = tid & 1023;
  const int r   = tid >> 10;            // b*nslot + s
  const int s   = r % nslot;
  const int b   = r / nslot;
  const int c0  = s << 1;
  const int C   = nslot << 1;

  float a0 = 0.f, a1 = 0.f, b0 = 0.f, b1 = 0.f;
  if (t < nxb) {
    float2 p = spart[(c0 << 8) + t];
    float2 q = spart[((c0 + 1) << 8) + t];
    a0 = p.x; a1 = p.y; b0 = q.x; b1 = q.y;
  }
#pragma unroll
  for (int off = 32; off > 0; off >>= 1) {
    a0 += __shfl_down(a0, off); a1 += __shfl_down(a1, off);
    b0 += __shfl_down(b0, off); b1 += __shfl_down(b1, off);
  }
  __shared__ float red[4][4];
  if ((t & 63) == 0) { int w = t >> 6; red[w][0] = a0; red[w][1] = a1; red[w][2] = b0; red[w][3] = b1; }
  __syncthreads();
  a0 = red[0][0] + red[1][0] + red[2][0] + red[3][0];
  a1 = red[0][1] + red[1][1] + red[2][1] + red[3][1];
  b0 = red[0][2] + red[1][2] + red[2][2] + red[3][2];
  b1 = red[0][3] + red[1][3] + red[2][3] + red[3][3];
  const float invN = 1.0f / NTOT;
  float m0 = a0 * invN, m1 = b0 * invN;
  float r0 = rsqrtf(a1 * invN - m0 * m0 + 1e-5f);
  float r1 = rsqrtf(b1 * invN - m1 * m1 + 1e-5f);

  float va = y[(((size_t)(b * C + c0)) << 10) + n];
  float vc = y[(((size_t)(b * C + c0 + 1)) << 10) + n];
  float ta = fast_tanh((va - m0) * r0);
  float tc = fast_tanh((vc - m1) * r1);
  float as = ta * ta, cs = tc * tc;
  half8 h;
  h[0] = (_Float16)1.0f;
  h[1] = (_Float16)(ta + ta);
  h[2] = (_Float16)(3.75f * as - 0.75f);
  h[3] = (_Float16)(ta * (7.0f * as - 3.0f));
  h[4] = (_Float16)1.0f;
  h[5] = (_Float16)(tc + tc);
  h[6] = (_Float16)(3.75f * cs - 0.75f);
  h[7] = (_Float16)(tc * (7.0f * cs - 3.0f));
  PA[((size_t)r << 10) + n] = h;
}

// ---------- merged BN-finalize + in-place tanh (L7 input: t6, fp32) ----------
// Each block = one (b, c) row of 1024 elements.
__global__ __launch_bounds__(256) void act_tanh_ip(
    float* y, const float2* __restrict__ spart, int C, int nxb)
{
  const int bc = blockIdx.x;            // b*C + c
  const int c  = bc % C;
  const int t  = threadIdx.x;
  float sa = 0.f, sb = 0.f;
  if (t < nxb) { float2 p = spart[(c << 8) + t]; sa = p.x; sb = p.y; }
#pragma unroll
  for (int off = 32; off > 0; off >>= 1) {
    sa += __shfl_down(sa, off); sb += __shfl_down(sb, off);
  }
  __shared__ float red[4][2];
  if ((t & 63) == 0) { int w = t >> 6; red[w][0] = sa; red[w][1] = sb; }
  __syncthreads();
  sa = red[0][0] + red[1][0] + red[2][0] + red[3][0];
  sb = red[0][1] + red[1][1] + red[2][1] + red[3][1];
  const float invN = 1.0f / NTOT;
  float m = sa * invN;
  float rs = rsqrtf(sb * invN - m * m + 1e-5f);
  float4 v = *(float4*)(y + ((size_t)bc << 10) + (t << 2));
  v.x = fast_tanh((v.x - m) * rs);
  v.y = fast_tanh((v.y - m) * rs);
  v.z = fast_tanh((v.z - m) * rs);
  v.w = fast_tanh((v.w - m) * rs);
  *(float4*)(y + ((size_t)bc << 10) + (t << 2)) = v;
}

// ---------- MFMA KAN layer v5: PA input, 1-deep register-pipelined K-loop ----------
// Block: 128 pts x BN outs (BN = NBW*64), 2*NBW waves, 4x4 frags of 16x16x32.
// K-loop: issue next group's 8 half8 loads, MFMA current group, rotate -> loads
// stay in flight across the MFMA block (s_waitcnt lands at the rotate).
// Verified layouts: A m=lane&15, k=quad*8+j; C/D row(M)=quad*4+reg, col(N)=lane&15.
template<int NBW>
__global__ __launch_bounds__(NBW * 128) void kan_mfma5(
    const half8* __restrict__ PA,      // (B, nslot, N) poly frags
    const half8* __restrict__ wh,      // preconverted weights (x64)
    const float* __restrict__ bias,    // (B, C_out) or nullptr
    float*       __restrict__ out,     // (B, C_out, N) fp32 or nullptr (L5 mode)
    float2*      __restrict__ spart,   // (C_out, 256) partials
    float*       __restrict__ stat_acc,
    unsigned*    __restrict__ max_acc,
    int C_in, int C_out)
{
  constexpr int BN = NBW * 64;
  const int nslot = C_in >> 1;
  __shared__ float sredS[BN][2], sredS2[BN][2], sredM[BN][2];

  const int t    = threadIdx.x;
  const int lane = t & 63;
  const int col  = lane & 15;
  const int quad = lane >> 4;
  const int wv   = t >> 6;
  const int wm   = wv & 1;
  const int wn   = wv >> 1;
  const int b    = blockIdx.x >> 3;
  const int n0   = (blockIdx.x & 7) << 7;
  const int o0   = blockIdx.y * BN;

  f32x4 acc[4][4];
#pragma unroll
  for (int i = 0; i < 4; ++i)
#pragma unroll
    for (int j = 0; j < 4; ++j)
#pragma unroll
      for (int k = 0; k < 4; ++k) acc[i][j][k] = 0.0f;

  const half8* Ap = PA + (((size_t)(b * nslot + quad)) << 10) + n0 + (wm << 6) + col;
  const half8* Bp = wh + (size_t)blockIdx.y * nslot * BN + (size_t)quad * BN + wn * 64 + col;

  half8 af[4], bf[4];
#pragma unroll
  for (int f = 0; f < 4; ++f) { af[f] = Ap[f << 4]; bf[f] = Bp[f << 4]; }

  for (int s4 = 0; s4 + 4 < nslot; s4 += 4) {
    Ap += (size_t)4 << 10;
    Bp += (size_t)4 * BN;
    half8 afn[4], bfn[4];
#pragma unroll
    for (int f = 0; f < 4; ++f) { afn[f] = Ap[f << 4]; bfn[f] = Bp[f << 4]; }
#pragma unroll
    for (int fm = 0; fm < 4; ++fm)
#pragma unroll
      for (int fn = 0; fn < 4; ++fn)
        acc[fm][fn] = __builtin_amdgcn_mfma_f32_16x16x32_f16(af[fm], bf[fn], acc[fm][fn], 0, 0, 0);
#pragma unroll
    for (int f = 0; f < 4; ++f) { af[f] = afn[f]; bf[f] = bfn[f]; }
  }
#pragma unroll
  for (int fm = 0; fm < 4; ++fm)
#pragma unroll
    for (int fn = 0; fn < 4; ++fn)
      acc[fm][fn] = __builtin_amdgcn_mfma_f32_16x16x32_f16(af[fm], bf[fn], acc[fm][fn], 0, 0, 0);

  // ---- epilogue: unscale, bias, fp32 write, fused BN stats ----
  const float inv64 = 0.015625f;
#pragma unroll
  for (int fn = 0; fn < 4; ++fn) {
    const int cl = (wn << 6) + (fn << 4) + col;
    const int o  = o0 + cl;
    const float bb = bias ? bias[b * C_out + o] : 0.0f;
    float s = 0.f, s2 = 0.f, mx = -3.4e38f;
#pragma unroll
    for (int fm = 0; fm < 4; ++fm) {
      float v0 = acc[fm][fn][0] * inv64 + bb;
      float v1 = acc[fm][fn][1] * inv64 + bb;
      float v2 = acc[fm][fn][2] * inv64 + bb;
      float v3 = acc[fm][fn][3] * inv64 + bb;
      if (out) {
        *(float4*)(out + (((size_t)(b * C_out + o)) << 10) + n0 + (wm << 6) + (fm << 4) + (quad << 2)) =
            make_float4(v0, v1, v2, v3);
      }
      s  += v0 + v1 + v2 + v3;
      s2 += v0 * v0 + v1 * v1 + v2 * v2 + v3 * v3;
      mx  = fmaxf(fmaxf(v0, v1), fmaxf(fmaxf(v2, v3), mx));
    }
    s  += __shfl_down(s, 32);  s  += __shfl_down(s, 16);
    s2 += __shfl_down(s2, 32); s2 += __shfl_down(s2, 16);
    mx  = fmaxf(mx, __shfl_down(mx, 32)); mx = fmaxf(mx, __shfl_down(mx, 16));
    if (lane < 16) {
      sredS [cl][wm] = s;
      sredS2[cl][wm] = s2;
      sredM [cl][wm] = mx;
    }
  }
  __syncthreads();
  if (t < BN) {
    const int o = o0 + t;
    float s  = sredS [t][0] + sredS [t][1];
    float s2 = sredS2[t][0] + sredS2[t][1];
    if (out) {
      spart[(o << 8) + blockIdx.x] = make_float2(s, s2);
    } else {
      float mx = fmaxf(sredM[t][0], sredM[t][1]);
      atomicAdd(&stat_acc[o], s);
      atomicAdd(&stat_acc[C_out + o], s2);
      atomicMax(&max_acc[b * C_out + o], encf(mx));
    }
  }
}

// ---------- MFMA KAN layer v6: fp32 tanh input + inline Jacobi, pipelined (L7) ----------
template<int NBW>
__global__ __launch_bounds__(NBW * 128) void kan_mfma6(
    const float* __restrict__ T,       // (B, C_in, N) fp32 tanh values
    const half8* __restrict__ wh,
    float*       __restrict__ out,
    float2*      __restrict__ spart,
    int C_in, int C_out)
{
  constexpr int BN = NBW * 64;
  const int nslot = C_in >> 1;
  __shared__ float sredS[BN][2], sredS2[BN][2];

  const int t    = threadIdx.x;
  const int lane = t & 63;
  const int col  = lane & 15;
  const int quad = lane >> 4;
  const int wv   = t >> 6;
  const int wm   = wv & 1;
  const int wn   = wv >> 1;
  const int b    = blockIdx.x >> 3;
  const int n0   = (blockIdx.x & 7) << 7;
  const int o0   = blockIdx.y * BN;

  f32x4 acc[4][4];
#pragma unroll
  for (int i = 0; i < 4; ++i)
#pragma unroll
    for (int j = 0; j < 4; ++j)
#pragma unroll
      for (int k = 0; k < 4; ++k) acc[i][j][k] = 0.0f;

  const float* Tp = T + (((size_t)(b * C_in + (quad << 1))) << 10) + n0 + (wm << 6) + col;
  const half8* Bp = wh + (size_t)blockIdx.y * nslot * BN + (size_t)quad * BN + wn * 64 + col;

  float t0[4], t1[4];
  half8 bf[4];
#pragma unroll
  for (int f = 0; f < 4; ++f) {
    t0[f] = Tp[f << 4]; t1[f] = Tp[(f << 4) + 1024]; bf[f] = Bp[f << 4];
  }

  for (int s4 = 0; ; s4 += 4) {
    const bool more = (s4 + 4 < nslot);
    float t0n[4], t1n[4];
    half8 bfn[4];
    if (more) {
      Tp += (size_t)8 << 10;
      Bp += (size_t)4 * BN;
#pragma unroll
      for (int f = 0; f < 4; ++f) {
        t0n[f] = Tp[f << 4]; t1n[f] = Tp[(f << 4) + 1024]; bfn[f] = Bp[f << 4];
      }
    }
    half8 af[4];
#pragma unroll
    for (int f = 0; f < 4; ++f) {
      float a = t0[f], c = t1[f];
      float as = a * a, cs = c * c;
      half8 h;
      h[0] = (_Float16)1.0f;
      h[1] = (_Float16)(a + a);
      h[2] = (_Float16)(3.75f * as - 0.75f);
      h[3] = (_Float16)(a * (7.0f * as - 3.0f));
      h[4] = (_Float16)1.0f;
      h[5] = (_Float16)(c + c);
      h[6] = (_Float16)(3.75f * cs - 0.75f);
      h[7] = (_Float16)(c * (7.0f * cs - 3.0f));
      af[f] = h;
    }
#pragma unroll
    for (int fm = 0; fm < 4; ++fm)
#pragma unroll
      for (int fn = 0; fn < 4; ++fn)
        acc[fm][fn] = __builtin_amdgcn_mfma_f32_16x16x32_f16(af[fm], bf[fn], acc[fm][fn], 0, 0, 0);
    if (!more) break;
#pragma unroll
    for (int f = 0; f < 4; ++f) { t0[f] = t0n[f]; t1[f] = t1n[f]; bf[f] = bfn[f]; }
  }

  const float inv64 = 0.015625f;
#pragma unroll
  for (int fn = 0; fn < 4; ++fn) {
    const int cl = (wn << 6) + (fn << 4) + col;
    const int o  = o0 + cl;
    float s = 0.f, s2 = 0.f;
#pragma unroll
    for (int fm = 0; fm < 4; ++fm) {
      float v0 = acc[fm][fn][0] * inv64;
      float v1 = acc[fm][fn][1] * inv64;
      float v2 = acc[fm][fn][2] * inv64;
      float v3 = acc[fm][fn][3] * inv64;
      *(float4*)(out + (((size_t)(b * C_out + o)) << 10) + n0 + (wm << 6) + (fm << 4) + (quad << 2)) =
          make_float4(v0, v1, v2, v3);
      s  += v0 + v1 + v2 + v3;
      s2 += v0 * v0 + v1 * v1 + v2 * v2 + v3 * v3;
    }
    s  += __shfl_down(s, 32);  s  += __shfl_down(s, 16);
    s2 += __shfl_down(s2, 32); s2 += __shfl_down(s2, 16);
    if (lane < 16) { sredS[cl][wm] = s; sredS2[cl][wm] = s2; }
  }
  __syncthreads();
  if (t < BN) {
    const int o = o0 + t;
    spart[(o << 8) + blockIdx.x] =
        make_float2(sredS[t][0] + sredS[t][1], sredS2[t][0] + sredS2[t][1]);
  }
}

// ---------- fp32 KAN layer (L1 only: C_in=2) ----------
template<int BM, int BN>
__global__ __launch_bounds__(256) void kan_gemm(
    const float*  __restrict__ in, const float2* __restrict__ stats,
    const float*  __restrict__ w, float* __restrict__ out,
    float2* __restrict__ spart, int C_in, int C_out)
{
  static_assert(BM * BN == 256 * 64, "8x8-per-thread tile requires BM*BN == 16384");
  constexpr int TM = BM / 8;
  constexpr int AE = 8 * BM / 256;
  constexpr int BE = 8 * BN / 256;
  __shared__ __align__(16) float As[32][BM];
  __shared__ __align__(16) float Bs[32][BN];

  const int t  = threadIdx.x;
  const int tpb = NPTS / BM;
  const int b  = blockIdx.x / tpb;
  const int n0 = (blockIdx.x % tpb) * BM;
  const int o0 = blockIdx.y * BN;
  const int tm = t % TM;
  const int to = t / TM;

  float acc[2][4][2][4];
#pragma unroll
  for (int a = 0; a < 2; ++a)
#pragma unroll
    for (int c = 0; c < 4; ++c)
#pragma unroll
      for (int d = 0; d < 2; ++d)
#pragma unroll
        for (int e = 0; e < 4; ++e) acc[a][c][d][e] = 0.0f;

  const int nch = (C_in + 7) >> 3;
  for (int ch = 0; ch < nch; ++ch) {
    const int i0 = ch << 3;
    __syncthreads();
#pragma unroll
    for (int r = 0; r < AE; ++r) {
      int e  = t + (r << 8);
      int il = e / BM, n = e % BM;
      int i  = i0 + il;
      float p0 = 0.f, p1 = 0.f, p2 = 0.f, p3 = 0.f;
      if (i < C_in) {
        float v = in[((size_t)(b * C_in + i) << 10) + n0 + n];
        if (stats) { float2 s = stats[i]; v = (v - s.x) * s.y; }
        jacobi4(fast_tanh(v), p0, p1, p2, p3);
      }
      As[(il << 2) + 0][n] = p0;
      As[(il << 2) + 1][n] = p1;
      As[(il << 2) + 2][n] = p2;
      As[(il << 2) + 3][n] = p3;
    }
#pragma unroll
    for (int r = 0; r < BE; ++r) {
      int e  = t + (r << 8);
      int il = e / BN, o = e % BN;
      int i  = i0 + il;
      float4 wv = make_float4(0.f, 0.f, 0.f, 0.f);
      if (i < C_in) wv = *(const float4*)(w + (((size_t)i * C_out + o0 + o) << 2));
      Bs[(il << 2) + 0][o] = wv.x;
      Bs[(il << 2) + 1][o] = wv.y;
      Bs[(il << 2) + 2][o] = wv.z;
      Bs[(il << 2) + 3][o] = wv.w;
    }
    __syncthreads();
#pragma unroll 8
    for (int k = 0; k < 32; ++k) {
      const float4 a0 = *(const float4*)&As[k][tm << 2];
      const float4 a1 = *(const float4*)&As[k][(BM / 2) + (tm << 2)];
      const float4 b0 = *(const float4*)&Bs[k][to << 2];
      const float4 b1 = *(const float4*)&Bs[k][(BN / 2) + (to << 2)];
      const float am[2][4] = {{a0.x, a0.y, a0.z, a0.w}, {a1.x, a1.y, a1.z, a1.w}};
      const float bo[2][4] = {{b0.x, b0.y, b0.z, b0.w}, {b1.x, b1.y, b1.z, b1.w}};
#pragma unroll
      for (int oh = 0; oh < 2; ++oh)
#pragma unroll
        for (int oj = 0; oj < 4; ++oj) {
          const float bv = bo[oh][oj];
#pragma unroll
          for (int mh = 0; mh < 2; ++mh)
#pragma unroll
            for (int mj = 0; mj < 4; ++mj)
              acc[oh][oj][mh][mj] = fmaf(bv, am[mh][mj], acc[oh][oj][mh][mj]);
        }
    }
  }

#pragma unroll
  for (int oh = 0; oh < 2; ++oh)
#pragma unroll
    for (int oj = 0; oj < 4; ++oj) {
      const int o = o0 + oh * (BN / 2) + (to << 2) + oj;
      float s = 0.f, s2 = 0.f;
#pragma unroll
      for (int mh = 0; mh < 2; ++mh) {
        float4 v = make_float4(acc[oh][oj][mh][0], acc[oh][oj][mh][1],
                               acc[oh][oj][mh][2], acc[oh][oj][mh][3]);
        *(float4*)(out + (((size_t)(b * C_out + o)) << 10) + n0 + mh * (BM / 2) + (tm << 2)) = v;
        s  += v.x + v.y + v.z + v.w;
        s2 += v.x * v.x + v.y * v.y + v.z * v.z + v.w * v.w;
      }
#pragma unroll
      for (int off = TM / 2; off > 0; off >>= 1) {
        s  += __shfl_down(s, off, TM);
        s2 += __shfl_down(s2, off, TM);
      }
      if (tm == 0) spart[(o << 8) + blockIdx.x] = make_float2(s, s2);
    }
}

// ---------- finalize layer-5 stats from atomic accumulators ----------
__global__ void bn_finalize(const float* __restrict__ stat_acc,
                            float2* __restrict__ stats, int C) {
  int c = blockIdx.x * 256 + threadIdx.x;
  if (c < C) {
    float m   = stat_acc[c] * (1.0f / NTOT);
    float var = stat_acc[C + c] * (1.0f / NTOT) - m * m;
    stats[c] = make_float2(m, rsqrtf(var + 1e-5f));
  }
}

// ---------- global-feature branch of layer 6, parallel ----------
__global__ __launch_bounds__(256) void pool_const6p(
    const unsigned* __restrict__ max_acc, const float2* __restrict__ stats5,
    const float* __restrict__ w6, float* __restrict__ cst)
{
  __shared__ __align__(16) float4 P[32][64];
  const int t  = threadIdx.x;
  const int ot = blockIdx.x;
  const int c0 = blockIdx.y << 6;
#pragma unroll
  for (int it = 0; it < 8; ++it) {
    int idx = t + (it << 8);
    int b = idx >> 6, cl = idx & 63;
    int c = c0 + cl;
    float mx = decf(max_acc[(b << 10) + c]);
    float2 s = stats5[c];
    float tt = fast_tanh((mx - s.x) * s.y);
    float p0, p1, p2, p3; jacobi4(tt, p0, p1, p2, p3);
    P[b][cl] = make_float4(p0, p1, p2, p3);
  }
  __syncthreads();
  const int oL = t & 63;
  const int bg = t >> 6;
  const int o  = (ot << 6) + oL;
  float acc[8];
#pragma unroll
  for (int i = 0; i < 8; ++i) acc[i] = 0.f;
  for (int cl = 0; cl < 64; ++cl) {
    const float4 wv = *(const float4*)(w6 + (((size_t)(64 + c0 + cl) * 512 + o) << 2));
#pragma unroll
    for (int bb = 0; bb < 8; ++bb) {
      float4 p = P[(bg << 3) + bb][cl];
      acc[bb] += p.x * wv.x + p.y * wv.y + p.z * wv.z + p.w * wv.w;
    }
  }
#pragma unroll
  for (int bb = 0; bb < 8; ++bb)
    atomicAdd(&cst[(((bg << 3) + bb) << 9) + o], acc[bb]);
}

// ---------- final layer: PA9 (64 slots of fp16 polys) -> C_out=3 fp32 ----------
__global__ __launch_bounds__(256) void kan_final(
    const half8* __restrict__ PA, const float* __restrict__ w, float* __restrict__ out)
{
  int g = blockIdx.x * 256 + threadIdx.x;
  int b = g >> 10, n = g & 1023;
  float a0 = 0.f, a1 = 0.f, a2 = 0.f;
  for (int s = 0; s < 64; ++s) {
    half8 h = PA[(((size_t)(b * 64 + s)) << 10) + n];
#pragma unroll
    for (int half_i = 0; half_i < 2; ++half_i) {
      int i = (s << 1) + half_i;
      float p0 = (float)h[half_i * 4 + 0], p1 = (float)h[half_i * 4 + 1];
      float p2 = (float)h[half_i * 4 + 2], p3 = (float)h[half_i * 4 + 3];
      const float4 w0 = *(const float4*)(w + ((i * 3 + 0) << 2));
      const float4 w1 = *(const float4*)(w + ((i * 3 + 1) << 2));
      const float4 w2 = *(const float4*)(w + ((i * 3 + 2) << 2));
      a0 += p0 * w0.x + p1 * w0.y + p2 * w0.z + p3 * w0.w;
      a1 += p0 * w1.x + p1 * w1.y + p2 * w1.z + p3 * w1.w;
      a2 += p0 * w2.x + p1 * w2.y + p2 * w2.z + p3 * w2.w;
    }
  }
  out[((b * 3 + 0) << 10) + n] = a0;
  out[((b * 3 + 1) << 10) + n] = a1;
  out[((b * 3 + 2) << 10) + n] = a2;
}

// ---------- launch ----------
extern "C" void kernel_launch(void* const* d_in, const int* in_sizes, int n_in,
                              void* d_out, int out_size, void* d_ws, size_t ws_size,
                              hipStream_t stream) {
  const float* x   = (const float*)d_in[0];
  const float* w1  = (const float*)d_in[1];
  const float* w2  = (const float*)d_in[2];
  const float* w3  = (const float*)d_in[3];
  const float* w4  = (const float*)d_in[4];
  const float* w5  = (const float*)d_in[5];
  const float* w6  = (const float*)d_in[6];
  const float* w7  = (const float*)d_in[7];
  const float* w8  = (const float*)d_in[8];
  const float* w9  = (const float*)d_in[9];
  const float* w10 = (const float*)d_in[10];

  float* ws = (float*)d_ws;
  // misc region (floats)
  float*    stat_acc = ws + 0;                      // 2048
  unsigned* maxenc   = (unsigned*)(ws + 2048);      // 32768
  float*    cst6     = ws + 34816;                  // 16384 (zeroed)
  float2*   spart    = (float2*)(ws + 51200);       // 131072 float2 -> ends 313344
  float2*   stats5   = (float2*)(ws + 313344);      // 1024 float2
  // fp16 weight pool (half8 units) @ float offset 318464 (ends 1039360 < 1048576)
  half8*    whbase = (half8*)(ws + 318464);
  half8*    h2 = whbase + 0;        // 2048
  half8*    h3 = whbase + 2048;     // 2048
  half8*    h4 = whbase + 4096;     // 4096
  half8*    h5 = whbase + 8192;     // 65536
  half8*    h6 = whbase + 73728;    // 16384
  half8*    h7 = whbase + 90112;    // 65536
  half8*    h8 = whbase + 155648;   // 16384
  half8*    h9 = whbase + 172032;   // 8192
  // data regions (floats), liveness-scheduled tenants:
  //  A (16M fl): y1[0..2M] -> PA4[0..8M] -> y6/t6[0..16M] -> PA7[0..16M]
  //  B (8M fl):  PA1[0..4M]+y2[4..6M] -> PA3[0..4M]+y3[4..6M] -> y7[0..8M]
  //              -> PA8[0..8M] -> PA9[0..8M]
  //  C (8M fl):  PA2[0..4M] (act2..L6) + y4[4..8M] -> y8[0..4M] + y9[4..8M]
  float* P  = ws + 1048576;
  float* A  = P;
  float* B  = P + 16777216;
  float* C  = P + 25165824;         // ends P+32M -> total ~132 MB
  float* y1  = A;
  half8* PA4 = (half8*)A;
  float* y6  = A;
  half8* PA7 = (half8*)A;
  half8* PA1 = (half8*)B;
  float* y2  = B + 4194304;
  half8* PA3 = (half8*)B;
  float* y3  = B + 4194304;
  float* y7  = B;
  half8* PA8 = (half8*)B;
  half8* PA9 = (half8*)B;
  half8* PA2 = (half8*)C;
  float* y4  = C + 4194304;
  float* y8  = C;
  float* y9  = C + 4194304;

  dim3 blk(256);
  zero_ws<<<200, blk, 0, stream>>>((unsigned*)ws, 51200);
  // preconvert weights
  conv_w16<<<8,   blk, 0, stream>>>(w2, h2, 64, 64, 64);
  conv_w16<<<8,   blk, 0, stream>>>(w3, h3, 64, 64, 64);
  conv_w16<<<16,  blk, 0, stream>>>(w4, h4, 64, 128, 128);
  conv_w16<<<256, blk, 0, stream>>>(w5, h5, 128, 1024, 128);
  conv_w16<<<64,  blk, 0, stream>>>(w6, h6, 64, 512, 128);   // local rows 0..63
  conv_w16<<<256, blk, 0, stream>>>(w7, h7, 512, 256, 128);
  conv_w16<<<64,  blk, 0, stream>>>(w8, h8, 256, 128, 128);
  conv_w16<<<32,  blk, 0, stream>>>(w9, h9, 128, 128, 128);

  // L1: 2 -> 64 fp32 (grid.x = 128 -> nxb = 128)
  kan_gemm<256, 64><<<dim3(128, 1), blk, 0, stream>>>(x, nullptr, w1, y1, spart, 2, 64);
  act_poly<<<128 * 32, blk, 0, stream>>>(y1, spart, PA1, 32, 128);
  // L2: 64 -> 64
  kan_mfma5<1><<<dim3(256, 1), 128, 0, stream>>>(PA1, h2, nullptr, y2, spart, nullptr, nullptr, 64, 64);
  act_poly<<<128 * 32, blk, 0, stream>>>(y2, spart, PA2, 32, 256);           // PA2 kept for L6
  // L3: 64 -> 64
  kan_mfma5<1><<<dim3(256, 1), 128, 0, stream>>>(PA2, h3, nullptr, y3, spart, nullptr, nullptr, 64, 64);
  act_poly<<<128 * 32, blk, 0, stream>>>(y3, spart, PA3, 32, 256);
  // L4: 64 -> 128
  kan_mfma5<2><<<dim3(256, 1), blk, 0, stream>>>(PA3, h4, nullptr, y4, spart, nullptr, nullptr, 64, 128);
  act_poly<<<128 * 64, blk, 0, stream>>>(y4, spart, PA4, 64, 256);
  // L5: 128 -> 1024, fused stats + maxpool, no materialization
  kan_mfma5<2><<<dim3(256, 8), blk, 0, stream>>>(PA4, h5, nullptr, nullptr, nullptr, stat_acc, maxenc, 128, 1024);
  bn_finalize<<<4, blk, 0, stream>>>(stat_acc, stats5, 1024);
  // gf branch of layer 6
  pool_const6p<<<dim3(8, 16), blk, 0, stream>>>(maxenc, stats5, w6, cst6);
  // L6: 64 (local, PA2) -> 512 + gf bias
  kan_mfma5<2><<<dim3(256, 4), blk, 0, stream>>>(PA2, h6, cst6, y6, spart, nullptr, nullptr, 64, 512);
  act_tanh_ip<<<32 * 512, blk, 0, stream>>>(y6, spart, 512, 256);            // t6 in place
  // L7: 512 -> 256 (inline Jacobi from fp32 t6, pipelined)
  kan_mfma6<2><<<dim3(256, 2), blk, 0, stream>>>(y6, h7, y7, spart, 512, 256);
  act_poly<<<128 * 128, blk, 0, stream>>>(y7, spart, PA7, 128, 256);
  // L8: 256 -> 128
  kan_mfma5<2><<<dim3(256, 1), blk, 0, stream>>>(PA7, h8, nullptr, y8, spart, nullptr, nullptr, 256, 128);
  act_poly<<<128 * 64, blk, 0, stream>>>(y8, spart, PA8, 64, 256);
  // L9: 128 -> 128
  kan_mfma5<2><<<dim3(256, 1), blk, 0, stream>>>(PA8, h9, nullptr, y9, spart, nullptr, nullptr, 128, 128);
  act_poly<<<128 * 64, blk, 0, stream>>>(y9, spart, PA9, 64, 256);
  // L10: 128 -> 3 (fp16 polys x fp32 weights)
  kan_final<<<128, blk, 0, stream>>>(PA9, w10, (float*)d_out);
}

// Round 10
// 448.135 us; speedup vs baseline: 1.0886x; 1.0006x over previous
//
#include <hip/hip_runtime.h>

#define BATCH 32
#define NPTS  1024
#define NTOT  (BATCH * NPTS)   // 32768 points

typedef _Float16 half8  __attribute__((ext_vector_type(8)));
typedef float    f32x4  __attribute__((ext_vector_type(4)));

// ---------- helpers ----------

__device__ __forceinline__ float fast_tanh(float x) {
  float ax = fabsf(x);
  float e  = __expf(-2.0f * ax);
  float t  = (1.0f - e) / (1.0f + e);
  return x < 0.0f ? -t : t;
}

// Jacobi polys for a=b=1, degree 3: p1=2t, p2=3.75t^2-0.75, p3=7t^3-3t
__device__ __forceinline__ void jacobi4(float t, float& p0, float& p1, float& p2, float& p3) {
  float t2 = t * t;
  p0 = 1.0f;
  p1 = 2.0f * t;
  p2 = 3.75f * t2 - 0.75f;
  p3 = t * (7.0f * t2 - 3.0f);
}

// monotone float<->uint encoding for atomicMax over signed floats
__device__ __forceinline__ unsigned encf(float f) {
  unsigned b = __float_as_uint(f);
  return b ^ ((unsigned)((int)b >> 31) | 0x80000000u);
}
__device__ __forceinline__ float decf(unsigned u) {
  unsigned b = (u & 0x80000000u) ? (u ^ 0x80000000u) : ~u;
  return __uint_as_float(b);
}

// ---------- zero workspace accumulators ----------
__global__ void zero_ws(unsigned* __restrict__ p, int n) {
  int i = blockIdx.x * 256 + threadIdx.x;
  if (i < n) p[i] = 0u;
}

// ---------- weight preconversion: fp32 (C_in, C_out, 4) -> fp16 x64, fragment layout ----------
__global__ void conv_w16(const float* __restrict__ w, half8* __restrict__ wh,
                         int C_in, int C_out, int BN) {
  const int nslot = C_in >> 1;
  int tid = blockIdx.x * 256 + threadIdx.x;
  int oL = tid % BN;
  int r  = tid / BN;
  int s  = r % nslot;
  int ot = r / nslot;
  int i  = s << 1;
  int o  = ot * BN + oL;
  const float4 wa = *(const float4*)(w + (((size_t)i * C_out + o) << 2));
  const float4 wb = *(const float4*)(w + (((size_t)(i + 1) * C_out + o) << 2));
  half8 h;
  h[0] = (_Float16)(wa.x * 64.0f); h[1] = (_Float16)(wa.y * 64.0f);
  h[2] = (_Float16)(wa.z * 64.0f); h[3] = (_Float16)(wa.w * 64.0f);
  h[4] = (_Float16)(wb.x * 64.0f); h[5] = (_Float16)(wb.y * 64.0f);
  h[6] = (_Float16)(wb.z * 64.0f); h[7] = (_Float16)(wb.w * 64.0f);
  wh[tid] = h;
}

// ---------- merged BN-finalize + activation+poly: y fp32 -> PA half8 (A-frag layout) ----------
__global__ __launch_bounds__(256) void act_poly(
    const float* __restrict__ y, const float2* __restrict__ spart,
    half8* __restrict__ PA, int nslot, int nxb)
{
  const int tid = blockIdx.x * 256 + threadIdx.x;
  const int t   = threadIdx.x;
  const int n   = tid & 1023;
  const int r   = tid >> 10;            // b*nslot + s
  const int s   = r % nslot;
  const int b   = r / nslot;
  const int c0  = s << 1;
  const int C   = nslot << 1;

  float a0 = 0.f, a1 = 0.f, b0 = 0.f, b1 = 0.f;
  if (t < nxb) {
    float2 p = spart[(c0 << 8) + t];
    float2 q = spart[((c0 + 1) << 8) + t];
    a0 = p.x; a1 = p.y; b0 = q.x; b1 = q.y;
  }
#pragma unroll
  for (int off = 32; off > 0; off >>= 1) {
    a0 += __shfl_down(a0, off); a1 += __shfl_down(a1, off);
    b0 += __shfl_down(b0, off); b1 += __shfl_down(b1, off);
  }
  __shared__ float red[4][4];
  if ((t & 63) == 0) { int w = t >> 6; red[w][0] = a0; red[w][1] = a1; red[w][2] = b0; red[w][3] = b1; }
  __syncthreads();
  a0 = red[0][0] + red[1][0] + red[2][0] + red[3][0];
  a1 = red[0][1] + red[1][1] + red[2][1] + red[3][1];
  b0 = red[0][2] + red[1][2] + red[2][2] + red[3][2];
  b1 = red[0][3] + red[1][3] + red[2][3] + red[3][3];
  const float invN = 1.0f / NTOT;
  float m0 = a0 * invN, m1 = b0 * invN;
  float r0 = rsqrtf(a1 * invN - m0 * m0 + 1e-5f);
  float r1 = rsqrtf(b1 * invN - m1 * m1 + 1e-5f);

  float va = y[(((size_t)(b * C + c0)) << 10) + n];
  float vc = y[(((size_t)(b * C + c0 + 1)) << 10) + n];
  float ta = fast_tanh((va - m0) * r0);
  float tc = fast_tanh((vc - m1) * r1);
  float as = ta * ta, cs = tc * tc;
  half8 h;
  h[0] = (_Float16)1.0f;
  h[1] = (_Float16)(ta + ta);
  h[2] = (_Float16)(3.75f * as - 0.75f);
  h[3] = (_Float16)(ta * (7.0f * as - 3.0f));
  h[4] = (_Float16)1.0f;
  h[5] = (_Float16)(tc + tc);
  h[6] = (_Float16)(3.75f * cs - 0.75f);
  h[7] = (_Float16)(tc * (7.0f * cs - 3.0f));
  PA[((size_t)r << 10) + n] = h;
}

// ---------- merged BN-finalize + in-place tanh (L7 input: t6, fp32) ----------
__global__ __launch_bounds__(256) void act_tanh_ip(
    float* y, const float2* __restrict__ spart, int C, int nxb)
{
  const int bc = blockIdx.x;            // b*C + c
  const int c  = bc % C;
  const int t  = threadIdx.x;
  float sa = 0.f, sb = 0.f;
  if (t < nxb) { float2 p = spart[(c << 8) + t]; sa = p.x; sb = p.y; }
#pragma unroll
  for (int off = 32; off > 0; off >>= 1) {
    sa += __shfl_down(sa, off); sb += __shfl_down(sb, off);
  }
  __shared__ float red[4][2];
  if ((t & 63) == 0) { int w = t >> 6; red[w][0] = sa; red[w][1] = sb; }
  __syncthreads();
  sa = red[0][0] + red[1][0] + red[2][0] + red[3][0];
  sb = red[0][1] + red[1][1] + red[2][1] + red[3][1];
  const float invN = 1.0f / NTOT;
  float m = sa * invN;
  float rs = rsqrtf(sb * invN - m * m + 1e-5f);
  float4 v = *(float4*)(y + ((size_t)bc << 10) + (t << 2));
  v.x = fast_tanh((v.x - m) * rs);
  v.y = fast_tanh((v.y - m) * rs);
  v.z = fast_tanh((v.z - m) * rs);
  v.w = fast_tanh((v.w - m) * rs);
  *(float4*)(y + ((size_t)bc << 10) + (t << 2)) = v;
}

// ---------- MFMA KAN layer v7: PA input, x2-unrolled ping-pong K-loop (no rotate movs) ----------
// Consume-then-refill: mfma(buf0); load g+2 -> buf0; mfma(buf1); load g+3 -> buf1.
// Each refill's loads are covered by the other buffer's 16-MFMA burst.
// ngroups = nslot/4 is even for all layers (8..64).
template<int NBW>
__global__ __launch_bounds__(NBW * 128) void kan_mfma5(
    const half8* __restrict__ PA,      // (B, nslot, N) poly frags
    const half8* __restrict__ wh,      // preconverted weights (x64)
    const float* __restrict__ bias,    // (B, C_out) or nullptr
    float*       __restrict__ out,     // (B, C_out, N) fp32 or nullptr (L5 mode)
    float2*      __restrict__ spart,   // (C_out, 256) partials
    float*       __restrict__ stat_acc,
    unsigned*    __restrict__ max_acc,
    int C_in, int C_out)
{
  constexpr int BN = NBW * 64;
  const int nslot = C_in >> 1;
  const int ngroups = nslot >> 2;
  __shared__ float sredS[BN][2], sredS2[BN][2], sredM[BN][2];

  const int t    = threadIdx.x;
  const int lane = t & 63;
  const int col  = lane & 15;
  const int quad = lane >> 4;
  const int wv   = t >> 6;
  const int wm   = wv & 1;
  const int wn   = wv >> 1;
  const int b    = blockIdx.x >> 3;
  const int n0   = (blockIdx.x & 7) << 7;
  const int o0   = blockIdx.y * BN;

  f32x4 acc[4][4];
#pragma unroll
  for (int i = 0; i < 4; ++i)
#pragma unroll
    for (int j = 0; j < 4; ++j)
#pragma unroll
      for (int k = 0; k < 4; ++k) acc[i][j][k] = 0.0f;

  const half8* Ap = PA + (((size_t)(b * nslot + quad)) << 10) + n0 + (wm << 6) + col;
  const half8* Bp = wh + (size_t)blockIdx.y * nslot * BN + (size_t)quad * BN + wn * 64 + col;

  half8 a0[4], b0[4], a1[4], b1[4];
#pragma unroll
  for (int f = 0; f < 4; ++f) { a0[f] = Ap[f << 4]; b0[f] = Bp[f << 4]; }
  {
    const half8* An = Ap + ((size_t)1 << 12);
    const half8* Bn = Bp + (size_t)4 * BN;
#pragma unroll
    for (int f = 0; f < 4; ++f) { a1[f] = An[f << 4]; b1[f] = Bn[f << 4]; }
  }

  for (int g = 0; g + 2 < ngroups; g += 2) {
#pragma unroll
    for (int fm = 0; fm < 4; ++fm)
#pragma unroll
      for (int fn = 0; fn < 4; ++fn)
        acc[fm][fn] = __builtin_amdgcn_mfma_f32_16x16x32_f16(a0[fm], b0[fn], acc[fm][fn], 0, 0, 0);
    {
      const half8* An = Ap + ((size_t)(g + 2) << 12);
      const half8* Bn = Bp + (size_t)(g + 2) * 4 * BN;
#pragma unroll
      for (int f = 0; f < 4; ++f) { a0[f] = An[f << 4]; b0[f] = Bn[f << 4]; }
    }
#pragma unroll
    for (int fm = 0; fm < 4; ++fm)
#pragma unroll
      for (int fn = 0; fn < 4; ++fn)
        acc[fm][fn] = __builtin_amdgcn_mfma_f32_16x16x32_f16(a1[fm], b1[fn], acc[fm][fn], 0, 0, 0);
    {
      const half8* An = Ap + ((size_t)(g + 3) << 12);
      const half8* Bn = Bp + (size_t)(g + 3) * 4 * BN;
#pragma unroll
      for (int f = 0; f < 4; ++f) { a1[f] = An[f << 4]; b1[f] = Bn[f << 4]; }
    }
  }
#pragma unroll
  for (int fm = 0; fm < 4; ++fm)
#pragma unroll
    for (int fn = 0; fn < 4; ++fn)
      acc[fm][fn] = __builtin_amdgcn_mfma_f32_16x16x32_f16(a0[fm], b0[fn], acc[fm][fn], 0, 0, 0);
#pragma unroll
  for (int fm = 0; fm < 4; ++fm)
#pragma unroll
    for (int fn = 0; fn < 4; ++fn)
      acc[fm][fn] = __builtin_amdgcn_mfma_f32_16x16x32_f16(a1[fm], b1[fn], acc[fm][fn], 0, 0, 0);

  // ---- epilogue: unscale, bias, fp32 write, fused BN stats ----
  const float inv64 = 0.015625f;
#pragma unroll
  for (int fn = 0; fn < 4; ++fn) {
    const int cl = (wn << 6) + (fn << 4) + col;
    const int o  = o0 + cl;
    const float bb = bias ? bias[b * C_out + o] : 0.0f;
    float s = 0.f, s2 = 0.f, mx = -3.4e38f;
#pragma unroll
    for (int fm = 0; fm < 4; ++fm) {
      float v0 = acc[fm][fn][0] * inv64 + bb;
      float v1 = acc[fm][fn][1] * inv64 + bb;
      float v2 = acc[fm][fn][2] * inv64 + bb;
      float v3 = acc[fm][fn][3] * inv64 + bb;
      if (out) {
        *(float4*)(out + (((size_t)(b * C_out + o)) << 10) + n0 + (wm << 6) + (fm << 4) + (quad << 2)) =
            make_float4(v0, v1, v2, v3);
      }
      s  += v0 + v1 + v2 + v3;
      s2 += v0 * v0 + v1 * v1 + v2 * v2 + v3 * v3;
      mx  = fmaxf(fmaxf(v0, v1), fmaxf(fmaxf(v2, v3), mx));
    }
    s  += __shfl_down(s, 32);  s  += __shfl_down(s, 16);
    s2 += __shfl_down(s2, 32); s2 += __shfl_down(s2, 16);
    mx  = fmaxf(mx, __shfl_down(mx, 32)); mx = fmaxf(mx, __shfl_down(mx, 16));
    if (lane < 16) {
      sredS [cl][wm] = s;
      sredS2[cl][wm] = s2;
      sredM [cl][wm] = mx;
    }
  }
  __syncthreads();
  if (t < BN) {
    const int o = o0 + t;
    float s  = sredS [t][0] + sredS [t][1];
    float s2 = sredS2[t][0] + sredS2[t][1];
    if (out) {
      spart[(o << 8) + blockIdx.x] = make_float2(s, s2);
    } else {
      float mx = fmaxf(sredM[t][0], sredM[t][1]);
      atomicAdd(&stat_acc[o], s);
      atomicAdd(&stat_acc[C_out + o], s2);
      atomicMax(&max_acc[b * C_out + o], encf(mx));
    }
  }
}

// ---------- MFMA KAN layer v8: fp32 tanh input + inline Jacobi, x2-unrolled ping-pong (L7) ----------
template<int NBW>
__global__ __launch_bounds__(NBW * 128) void kan_mfma6(
    const float* __restrict__ T,       // (B, C_in, N) fp32 tanh values
    const half8* __restrict__ wh,
    float*       __restrict__ out,
    float2*      __restrict__ spart,
    int C_in, int C_out)
{
  constexpr int BN = NBW * 64;
  const int nslot = C_in >> 1;
  const int ngroups = nslot >> 2;
  __shared__ float sredS[BN][2], sredS2[BN][2];

  const int t    = threadIdx.x;
  const int lane = t & 63;
  const int col  = lane & 15;
  const int quad = lane >> 4;
  const int wv   = t >> 6;
  const int wm   = wv & 1;
  const int wn   = wv >> 1;
  const int b    = blockIdx.x >> 3;
  const int n0   = (blockIdx.x & 7) << 7;
  const int o0   = blockIdx.y * BN;

  f32x4 acc[4][4];
#pragma unroll
  for (int i = 0; i < 4; ++i)
#pragma unroll
    for (int j = 0; j < 4; ++j)
#pragma unroll
      for (int k = 0; k < 4; ++k) acc[i][j][k] = 0.0f;

  const float* Tp = T + (((size_t)(b * C_in + (quad << 1))) << 10) + n0 + (wm << 6) + col;
  const half8* Bp = wh + (size_t)blockIdx.y * nslot * BN + (size_t)quad * BN + wn * 64 + col;

  float t00[4], t10[4], t01[4], t11[4];
  half8 bf0[4], bf1[4];
#pragma unroll
  for (int f = 0; f < 4; ++f) {
    t00[f] = Tp[f << 4]; t10[f] = Tp[(f << 4) + 1024]; bf0[f] = Bp[f << 4];
  }
  {
    const float* Tn = Tp + ((size_t)1 << 13);
    const half8* Bn = Bp + (size_t)4 * BN;
#pragma unroll
    for (int f = 0; f < 4; ++f) {
      t01[f] = Tn[f << 4]; t11[f] = Tn[(f << 4) + 1024]; bf1[f] = Bn[f << 4];
    }
  }

#define MFMA6_CONSUME(T0, T1, BF)                                               \
  {                                                                             \
    half8 af[4];                                                                \
    _Pragma("unroll")                                                           \
    for (int f = 0; f < 4; ++f) {                                               \
      float a = T0[f], c = T1[f];                                               \
      float as = a * a, cs = c * c;                                             \
      half8 h;                                                                  \
      h[0] = (_Float16)1.0f;                                                    \
      h[1] = (_Float16)(a + a);                                                 \
      h[2] = (_Float16)(3.75f * as - 0.75f);                                    \
      h[3] = (_Float16)(a * (7.0f * as - 3.0f));                                \
      h[4] = (_Float16)1.0f;                                                    \
      h[5] = (_Float16)(c + c);                                                 \
      h[6] = (_Float16)(3.75f * cs - 0.75f);                                    \
      h[7] = (_Float16)(c * (7.0f * cs - 3.0f));                                \
      af[f] = h;                                                                \
    }                                                                           \
    _Pragma("unroll")                                                           \
    for (int fm = 0; fm < 4; ++fm)                                              \
      _Pragma("unroll")                                                         \
      for (int fn = 0; fn < 4; ++fn)                                            \
        acc[fm][fn] = __builtin_amdgcn_mfma_f32_16x16x32_f16(af[fm], BF[fn], acc[fm][fn], 0, 0, 0); \
  }

  for (int g = 0; g + 2 < ngroups; g += 2) {
    MFMA6_CONSUME(t00, t10, bf0)
    {
      const float* Tn = Tp + ((size_t)(g + 2) << 13);
      const half8* Bn = Bp + (size_t)(g + 2) * 4 * BN;
#pragma unroll
      for (int f = 0; f < 4; ++f) {
        t00[f] = Tn[f << 4]; t10[f] = Tn[(f << 4) + 1024]; bf0[f] = Bn[f << 4];
      }
    }
    MFMA6_CONSUME(t01, t11, bf1)
    {
      const float* Tn = Tp + ((size_t)(g + 3) << 13);
      const half8* Bn = Bp + (size_t)(g + 3) * 4 * BN;
#pragma unroll
      for (int f = 0; f < 4; ++f) {
        t01[f] = Tn[f << 4]; t11[f] = Tn[(f << 4) + 1024]; bf1[f] = Bn[f << 4];
      }
    }
  }
  MFMA6_CONSUME(t00, t10, bf0)
  MFMA6_CONSUME(t01, t11, bf1)
#undef MFMA6_CONSUME

  const float inv64 = 0.015625f;
#pragma unroll
  for (int fn = 0; fn < 4; ++fn) {
    const int cl = (wn << 6) + (fn << 4) + col;
    const int o  = o0 + cl;
    float s = 0.f, s2 = 0.f;
#pragma unroll
    for (int fm = 0; fm < 4; ++fm) {
      float v0 = acc[fm][fn][0] * inv64;
      float v1 = acc[fm][fn][1] * inv64;
      float v2 = acc[fm][fn][2] * inv64;
      float v3 = acc[fm][fn][3] * inv64;
      *(float4*)(out + (((size_t)(b * C_out + o)) << 10) + n0 + (wm << 6) + (fm << 4) + (quad << 2)) =
          make_float4(v0, v1, v2, v3);
      s  += v0 + v1 + v2 + v3;
      s2 += v0 * v0 + v1 * v1 + v2 * v2 + v3 * v3;
    }
    s  += __shfl_down(s, 32);  s  += __shfl_down(s, 16);
    s2 += __shfl_down(s2, 32); s2 += __shfl_down(s2, 16);
    if (lane < 16) { sredS[cl][wm] = s; sredS2[cl][wm] = s2; }
  }
  __syncthreads();
  if (t < BN) {
    const int o = o0 + t;
    spart[(o << 8) + blockIdx.x] =
        make_float2(sredS[t][0] + sredS[t][1], sredS2[t][0] + sredS2[t][1]);
  }
}

// ---------- fp32 KAN layer (L1 only: C_in=2) ----------
template<int BM, int BN>
__global__ __launch_bounds__(256) void kan_gemm(
    const float*  __restrict__ in, const float2* __restrict__ stats,
    const float*  __restrict__ w, float* __restrict__ out,
    float2* __restrict__ spart, int C_in, int C_out)
{
  static_assert(BM * BN == 256 * 64, "8x8-per-thread tile requires BM*BN == 16384");
  constexpr int TM = BM / 8;
  constexpr int AE = 8 * BM / 256;
  constexpr int BE = 8 * BN / 256;
  __shared__ __align__(16) float As[32][BM];
  __shared__ __align__(16) float Bs[32][BN];

  const int t  = threadIdx.x;
  const int tpb = NPTS / BM;
  const int b  = blockIdx.x / tpb;
  const int n0 = (blockIdx.x % tpb) * BM;
  const int o0 = blockIdx.y * BN;
  const int tm = t % TM;
  const int to = t / TM;

  float acc[2][4][2][4];
#pragma unroll
  for (int a = 0; a < 2; ++a)
#pragma unroll
    for (int c = 0; c < 4; ++c)
#pragma unroll
      for (int d = 0; d < 2; ++d)
#pragma unroll
        for (int e = 0; e < 4; ++e) acc[a][c][d][e] = 0.0f;

  const int nch = (C_in + 7) >> 3;
  for (int ch = 0; ch < nch; ++ch) {
    const int i0 = ch << 3;
    __syncthreads();
#pragma unroll
    for (int r = 0; r < AE; ++r) {
      int e  = t + (r << 8);
      int il = e / BM, n = e % BM;
      int i  = i0 + il;
      float p0 = 0.f, p1 = 0.f, p2 = 0.f, p3 = 0.f;
      if (i < C_in) {
        float v = in[((size_t)(b * C_in + i) << 10) + n0 + n];
        if (stats) { float2 s = stats[i]; v = (v - s.x) * s.y; }
        jacobi4(fast_tanh(v), p0, p1, p2, p3);
      }
      As[(il << 2) + 0][n] = p0;
      As[(il << 2) + 1][n] = p1;
      As[(il << 2) + 2][n] = p2;
      As[(il << 2) + 3][n] = p3;
    }
#pragma unroll
    for (int r = 0; r < BE; ++r) {
      int e  = t + (r << 8);
      int il = e / BN, o = e % BN;
      int i  = i0 + il;
      float4 wv = make_float4(0.f, 0.f, 0.f, 0.f);
      if (i < C_in) wv = *(const float4*)(w + (((size_t)i * C_out + o0 + o) << 2));
      Bs[(il << 2) + 0][o] = wv.x;
      Bs[(il << 2) + 1][o] = wv.y;
      Bs[(il << 2) + 2][o] = wv.z;
      Bs[(il << 2) + 3][o] = wv.w;
    }
    __syncthreads();
#pragma unroll 8
    for (int k = 0; k < 32; ++k) {
      const float4 a0 = *(const float4*)&As[k][tm << 2];
      const float4 a1 = *(const float4*)&As[k][(BM / 2) + (tm << 2)];
      const float4 b0 = *(const float4*)&Bs[k][to << 2];
      const float4 b1 = *(const float4*)&Bs[k][(BN / 2) + (to << 2)];
      const float am[2][4] = {{a0.x, a0.y, a0.z, a0.w}, {a1.x, a1.y, a1.z, a1.w}};
      const float bo[2][4] = {{b0.x, b0.y, b0.z, b0.w}, {b1.x, b1.y, b1.z, b1.w}};
#pragma unroll
      for (int oh = 0; oh < 2; ++oh)
#pragma unroll
        for (int oj = 0; oj < 4; ++oj) {
          const float bv = bo[oh][oj];
#pragma unroll
          for (int mh = 0; mh < 2; ++mh)
#pragma unroll
            for (int mj = 0; mj < 4; ++mj)
              acc[oh][oj][mh][mj] = fmaf(bv, am[mh][mj], acc[oh][oj][mh][mj]);
        }
    }
  }

#pragma unroll
  for (int oh = 0; oh < 2; ++oh)
#pragma unroll
    for (int oj = 0; oj < 4; ++oj) {
      const int o = o0 + oh * (BN / 2) + (to << 2) + oj;
      float s = 0.f, s2 = 0.f;
#pragma unroll
      for (int mh = 0; mh < 2; ++mh) {
        float4 v = make_float4(acc[oh][oj][mh][0], acc[oh][oj][mh][1],
                               acc[oh][oj][mh][2], acc[oh][oj][mh][3]);
        *(float4*)(out + (((size_t)(b * C_out + o)) << 10) + n0 + mh * (BM / 2) + (tm << 2)) = v;
        s  += v.x + v.y + v.z + v.w;
        s2 += v.x * v.x + v.y * v.y + v.z * v.z + v.w * v.w;
      }
#pragma unroll
      for (int off = TM / 2; off > 0; off >>= 1) {
        s  += __shfl_down(s, off, TM);
        s2 += __shfl_down(s2, off, TM);
      }
      if (tm == 0) spart[(o << 8) + blockIdx.x] = make_float2(s, s2);
    }
}

// ---------- finalize layer-5 stats from atomic accumulators ----------
__global__ void bn_finalize(const float* __restrict__ stat_acc,
                            float2* __restrict__ stats, int C) {
  int c = blockIdx.x * 256 + threadIdx.x;
  if (c < C) {
    float m   = stat_acc[c] * (1.0f / NTOT);
    float var = stat_acc[C + c] * (1.0f / NTOT) - m * m;
    stats[c] = make_float2(m, rsqrtf(var + 1e-5f));
  }
}

// ---------- global-feature branch of layer 6, parallel ----------
__global__ __launch_bounds__(256) void pool_const6p(
    const unsigned* __restrict__ max_acc, const float2* __restrict__ stats5,
    const float* __restrict__ w6, float* __restrict__ cst)
{
  __shared__ __align__(16) float4 P[32][64];
  const int t  = threadIdx.x;
  const int ot = blockIdx.x;
  const int c0 = blockIdx.y << 6;
#pragma unroll
  for (int it = 0; it < 8; ++it) {
    int idx = t + (it << 8);
    int b = idx >> 6, cl = idx & 63;
    int c = c0 + cl;
    float mx = decf(max_acc[(b << 10) + c]);
    float2 s = stats5[c];
    float tt = fast_tanh((mx - s.x) * s.y);
    float p0, p1, p2, p3; jacobi4(tt, p0, p1, p2, p3);
    P[b][cl] = make_float4(p0, p1, p2, p3);
  }
  __syncthreads();
  const int oL = t & 63;
  const int bg = t >> 6;
  const int o  = (ot << 6) + oL;
  float acc[8];
#pragma unroll
  for (int i = 0; i < 8; ++i) acc[i] = 0.f;
  for (int cl = 0; cl < 64; ++cl) {
    const float4 wv = *(const float4*)(w6 + (((size_t)(64 + c0 + cl) * 512 + o) << 2));
#pragma unroll
    for (int bb = 0; bb < 8; ++bb) {
      float4 p = P[(bg << 3) + bb][cl];
      acc[bb] += p.x * wv.x + p.y * wv.y + p.z * wv.z + p.w * wv.w;
    }
  }
#pragma unroll
  for (int bb = 0; bb < 8; ++bb)
    atomicAdd(&cst[(((bg << 3) + bb) << 9) + o], acc[bb]);
}

// ---------- final layer: PA9 (64 slots of fp16 polys) -> C_out=3 fp32 ----------
__global__ __launch_bounds__(256) void kan_final(
    const half8* __restrict__ PA, const float* __restrict__ w, float* __restrict__ out)
{
  int g = blockIdx.x * 256 + threadIdx.x;
  int b = g >> 10, n = g & 1023;
  float a0 = 0.f, a1 = 0.f, a2 = 0.f;
  for (int s = 0; s < 64; ++s) {
    half8 h = PA[(((size_t)(b * 64 + s)) << 10) + n];
#pragma unroll
    for (int half_i = 0; half_i < 2; ++half_i) {
      int i = (s << 1) + half_i;
      float p0 = (float)h[half_i * 4 + 0], p1 = (float)h[half_i * 4 + 1];
      float p2 = (float)h[half_i * 4 + 2], p3 = (float)h[half_i * 4 + 3];
      const float4 w0 = *(const float4*)(w + ((i * 3 + 0) << 2));
      const float4 w1 = *(const float4*)(w + ((i * 3 + 1) << 2));
      const float4 w2 = *(const float4*)(w + ((i * 3 + 2) << 2));
      a0 += p0 * w0.x + p1 * w0.y + p2 * w0.z + p3 * w0.w;
      a1 += p0 * w1.x + p1 * w1.y + p2 * w1.z + p3 * w1.w;
      a2 += p0 * w2.x + p1 * w2.y + p2 * w2.z + p3 * w2.w;
    }
  }
  out[((b * 3 + 0) << 10) + n] = a0;
  out[((b * 3 + 1) << 10) + n] = a1;
  out[((b * 3 + 2) << 10) + n] = a2;
}

// ---------- launch ----------
extern "C" void kernel_launch(void* const* d_in, const int* in_sizes, int n_in,
                              void* d_out, int out_size, void* d_ws, size_t ws_size,
                              hipStream_t stream) {
  const float* x   = (const float*)d_in[0];
  const float* w1  = (const float*)d_in[1];
  const float* w2  = (const float*)d_in[2];
  const float* w3  = (const float*)d_in[3];
  const float* w4  = (const float*)d_in[4];
  const float* w5  = (const float*)d_in[5];
  const float* w6  = (const float*)d_in[6];
  const float* w7  = (const float*)d_in[7];
  const float* w8  = (const float*)d_in[8];
  const float* w9  = (const float*)d_in[9];
  const float* w10 = (const float*)d_in[10];

  float* ws = (float*)d_ws;
  // misc region (floats)
  float*    stat_acc = ws + 0;                      // 2048
  unsigned* maxenc   = (unsigned*)(ws + 2048);      // 32768
  float*    cst6     = ws + 34816;                  // 16384 (zeroed)
  float2*   spart    = (float2*)(ws + 51200);       // 131072 float2 -> ends 313344
  float2*   stats5   = (float2*)(ws + 313344);      // 1024 float2
  // fp16 weight pool (half8 units) @ float offset 318464 (ends 1039360 < 1048576)
  half8*    whbase = (half8*)(ws + 318464);
  half8*    h2 = whbase + 0;        // 2048
  half8*    h3 = whbase + 2048;     // 2048
  half8*    h4 = whbase + 4096;     // 4096
  half8*    h5 = whbase + 8192;     // 65536
  half8*    h6 = whbase + 73728;    // 16384
  half8*    h7 = whbase + 90112;    // 65536
  half8*    h8 = whbase + 155648;   // 16384
  half8*    h9 = whbase + 172032;   // 8192
  // data regions (floats), liveness-scheduled tenants:
  //  A (16M fl): y1[0..2M] -> PA4[0..8M] -> y6/t6[0..16M] -> PA7[0..16M]
  //  B (8M fl):  PA1[0..4M]+y2[4..6M] -> PA3[0..4M]+y3[4..6M] -> y7[0..8M]
  //              -> PA8[0..8M] -> PA9[0..8M]
  //  C (8M fl):  PA2[0..4M] (act2..L6) + y4[4..8M] -> y8[0..4M] + y9[4..8M]
  float* P  = ws + 1048576;
  float* A  = P;
  float* B  = P + 16777216;
  float* C  = P + 25165824;         // ends P+32M -> total ~132 MB
  float* y1  = A;
  half8* PA4 = (half8*)A;
  float* y6  = A;
  half8* PA7 = (half8*)A;
  half8* PA1 = (half8*)B;
  float* y2  = B + 4194304;
  half8* PA3 = (half8*)B;
  float* y3  = B + 4194304;
  float* y7  = B;
  half8* PA8 = (half8*)B;
  half8* PA9 = (half8*)B;
  half8* PA2 = (half8*)C;
  float* y4  = C + 4194304;
  float* y8  = C;
  float* y9  = C + 4194304;

  dim3 blk(256);
  zero_ws<<<200, blk, 0, stream>>>((unsigned*)ws, 51200);
  // preconvert weights
  conv_w16<<<8,   blk, 0, stream>>>(w2, h2, 64, 64, 64);
  conv_w16<<<8,   blk, 0, stream>>>(w3, h3, 64, 64, 64);
  conv_w16<<<16,  blk, 0, stream>>>(w4, h4, 64, 128, 128);
  conv_w16<<<256, blk, 0, stream>>>(w5, h5, 128, 1024, 128);
  conv_w16<<<64,  blk, 0, stream>>>(w6, h6, 64, 512, 128);   // local rows 0..63
  conv_w16<<<256, blk, 0, stream>>>(w7, h7, 512, 256, 128);
  conv_w16<<<64,  blk, 0, stream>>>(w8, h8, 256, 128, 128);
  conv_w16<<<32,  blk, 0, stream>>>(w9, h9, 128, 128, 128);

  // L1: 2 -> 64 fp32 (grid.x = 128 -> nxb = 128)
  kan_gemm<256, 64><<<dim3(128, 1), blk, 0, stream>>>(x, nullptr, w1, y1, spart, 2, 64);
  act_poly<<<128 * 32, blk, 0, stream>>>(y1, spart, PA1, 32, 128);
  // L2: 64 -> 64
  kan_mfma5<1><<<dim3(256, 1), 128, 0, stream>>>(PA1, h2, nullptr, y2, spart, nullptr, nullptr, 64, 64);
  act_poly<<<128 * 32, blk, 0, stream>>>(y2, spart, PA2, 32, 256);           // PA2 kept for L6
  // L3: 64 -> 64
  kan_mfma5<1><<<dim3(256, 1), 128, 0, stream>>>(PA2, h3, nullptr, y3, spart, nullptr, nullptr, 64, 64);
  act_poly<<<128 * 32, blk, 0, stream>>>(y3, spart, PA3, 32, 256);
  // L4: 64 -> 128
  kan_mfma5<2><<<dim3(256, 1), blk, 0, stream>>>(PA3, h4, nullptr, y4, spart, nullptr, nullptr, 64, 128);
  act_poly<<<128 * 64, blk, 0, stream>>>(y4, spart, PA4, 64, 256);
  // L5: 128 -> 1024, fused stats + maxpool, no materialization
  kan_mfma5<2><<<dim3(256, 8), blk, 0, stream>>>(PA4, h5, nullptr, nullptr, nullptr, stat_acc, maxenc, 128, 1024);
  bn_finalize<<<4, blk, 0, stream>>>(stat_acc, stats5, 1024);
  // gf branch of layer 6
  pool_const6p<<<dim3(8, 16), blk, 0, stream>>>(maxenc, stats5, w6, cst6);
  // L6: 64 (local, PA2) -> 512 + gf bias
  kan_mfma5<2><<<dim3(256, 4), blk, 0, stream>>>(PA2, h6, cst6, y6, spart, nullptr, nullptr, 64, 512);
  act_tanh_ip<<<32 * 512, blk, 0, stream>>>(y6, spart, 512, 256);            // t6 in place
  // L7: 512 -> 256 (inline Jacobi from fp32 t6, pipelined)
  kan_mfma6<2><<<dim3(256, 2), blk, 0, stream>>>(y6, h7, y7, spart, 512, 256);
  act_poly<<<128 * 128, blk, 0, stream>>>(y7, spart, PA7, 128, 256);
  // L8: 256 -> 128
  kan_mfma5<2><<<dim3(256, 1), blk, 0, stream>>>(PA7, h8, nullptr, y8, spart, nullptr, nullptr, 256, 128);
  act_poly<<<128 * 64, blk, 0, stream>>>(y8, spart, PA8, 64, 256);
  // L9: 128 -> 128
  kan_mfma5<2><<<dim3(256, 1), blk, 0, stream>>>(PA8, h9, nullptr, y9, spart, nullptr, nullptr, 128, 128);
  act_poly<<<128 * 64, blk, 0, stream>>>(y9, spart, PA9, 64, 256);
  // L10: 128 -> 3 (fp16 polys x fp32 weights)
  kan_final<<<128, blk, 0, stream>>>(PA9, w10, (float*)d_out);
}